// Round 3
// baseline (620.853 us; speedup 1.0000x reference)
//
#include <hip/hip_runtime.h>
#include <math.h>

#pragma STDC FP_CONTRACT OFF

#define N 6000
#define NPAD 6144
#define C 81
#define PADDING 300
#define NMS_THRESH 0.5f
#define MASK_ELEMS (14 * 14 * 81) /* 15876 = 3969 float4 */
#define MASK_W 96                 /* u64 words per mask row (94 used; 96 keeps rows 16B-aligned) */
#define NCHUNK 8
#define CHUNK 750                 /* 6000 / 8 */

typedef unsigned long long u64;

// ---------------------------------------------------------------------------
// Kernel 1: decode — ONE WAVE PER PROPOSAL.
// Lane c reads score[c] (coalesced); shuffle-tree argmax with exact
// first-occurrence tie-break (prefer lower class on equal score); lane 0
// decodes the top class's box (float4 load: deltas row base n*1296B and
// 16*top B offset are both 16B-aligned) and emits the sort key.
// key = orderable(max_score)<<32 | ~n  => u64 desc == (score desc, idx asc).
// ---------------------------------------------------------------------------
__global__ void decode_kernel(const float* __restrict__ meta,
                              const float* __restrict__ deltas,
                              const float* __restrict__ proposals,
                              const float* __restrict__ scores,
                              float* __restrict__ pbox,
                              u64* __restrict__ skey) {
    int gw = blockIdx.x * 4 + (threadIdx.x >> 6);
    int lane = threadIdx.x & 63;
    if (gw >= N) return;

    const float* sr = scores + gw * C;
    float s0 = (lane < C) ? sr[lane] : -INFINITY;
    float s1 = (lane + 64 < C) ? sr[lane + 64] : -INFINITY;

    // per-lane best (s0 has the lower class index; wins ties)
    float bs;
    int bc;
    if (s1 > s0) { bs = s1; bc = lane + 64; } else { bs = s0; bc = lane; }
    // max over classes 1..C-1 (exclude class 0)
    float ms = fmaxf((lane == 0) ? -INFINITY : s0, s1);

    for (int off = 32; off > 0; off >>= 1) {
        float os = __shfl_down(bs, off);
        int oc = __shfl_down(bc, off);
        if (os > bs || (os == bs && oc < bc)) { bs = os; bc = oc; }
        ms = fmaxf(ms, __shfl_down(ms, off));
    }

    if (lane == 0) {
        float Hm = meta[0], Wm = meta[1], scale = meta[2];
        float4 pr = *(const float4*)(proposals + gw * 4);
        float b0 = pr.x / scale;
        float b1 = pr.y / scale;
        float b2 = pr.z / scale;
        float b3 = pr.w / scale;
        float w = b2 - b0 + 1.0f;
        float h = b3 - b1 + 1.0f;
        float cx = b0 + 0.5f * w;
        float cy = b1 + 0.5f * h;

        float4 dl = *(const float4*)(deltas + (size_t)gw * (4 * C) + 4 * bc);
        float pcx = dl.x * w + cx;
        float pcy = dl.y * h + cy;
        float pw = expf(dl.z) * w;
        float ph = expf(dl.w) * h;
        float x1 = pcx - 0.5f * pw;
        float y1 = pcy - 0.5f * ph;
        float x2 = pcx + 0.5f * pw;
        float y2 = pcy + 0.5f * ph;
        x1 = fminf(fmaxf(x1, 0.0f), Wm - 1.0f);
        y1 = fminf(fmaxf(y1, 0.0f), Hm - 1.0f);
        x2 = fminf(fmaxf(x2, 0.0f), Wm - 1.0f);
        y2 = fminf(fmaxf(y2, 0.0f), Hm - 1.0f);

        *(float4*)(pbox + gw * 4) = make_float4(x1, y1, x2, y2);

        unsigned int b = __float_as_uint(ms);
        unsigned int u = b ^ ((b & 0x80000000u) ? 0xFFFFFFFFu : 0x80000000u);
        skey[gw] = ((u64)u << 32) | (unsigned int)(~gw);
    }
}

// ---------------------------------------------------------------------------
// Kernel 2: brute-force rank (partial counts per key-chunk; no atomics).
// ---------------------------------------------------------------------------
__global__ void rank_kernel(const u64* __restrict__ skey,
                            int* __restrict__ rank_part) {
    __shared__ u64 lk[CHUNK];
    int chunk = blockIdx.y;
    int t = threadIdx.x;
    int j0 = chunk * CHUNK;
    for (int j = t; j < CHUNK; j += 256) lk[j] = skey[j0 + j];
    __syncthreads();

    int i = blockIdx.x * 256 + t;
    if (i >= N) return;
    u64 mykey = skey[i];
    int cnt = 0;
    for (int j = 0; j < CHUNK; ++j) cnt += (lk[j] > mykey) ? 1 : 0;
    rank_part[chunk * NPAD + i] = cnt;
}

// ---------------------------------------------------------------------------
// Kernel 3: scatter into sorted order (AoS float4 boxes for the IoU kernel).
// ---------------------------------------------------------------------------
__global__ void scatter_kernel(const int* __restrict__ rank_part,
                               const float* __restrict__ pbox,
                               int* __restrict__ sidx,
                               float4* __restrict__ sbox) {
    int i = blockIdx.x * blockDim.x + threadIdx.x;
    if (i >= N) return;
    int r = 0;
    for (int c = 0; c < NCHUNK; ++c) r += rank_part[c * NPAD + i];
    sidx[r] = i;
    sbox[r] = *(const float4*)(pbox + i * 4);
}

// ---------------------------------------------------------------------------
// Kernel 4: suppression bitmask — UPPER TRIANGLE ONLY.
// Scan is monotone-forward: when row p is OR'd, every bit < p is already 1,
// so sub-diagonal words may remain poison garbage (OR is harmless there).
// Row p writes words [p/64, 94). Wave g handles rows g and 5999-g so every
// pair costs ~95 words (load balance). Area recomputed with the exact
// reference expression (bit-identical to a stored copy).
// ---------------------------------------------------------------------------
__global__ void __launch_bounds__(256) iou_kernel(const float4* __restrict__ sbox,
                                                  u64* __restrict__ mask) {
    int g = blockIdx.x * 4 + (threadIdx.x >> 6);
    int lane = threadIdx.x & 63;
    if (g >= 3000) return;

#pragma unroll
    for (int which = 0; which < 2; ++which) {
        int p = which ? (N - 1 - g) : g;
        float4 B = sbox[p];  // broadcast load
        float war = (B.z - B.x + 1.0f) * (B.w - B.y + 1.0f);
        u64* row = mask + (size_t)p * MASK_W;
        for (int w = (p >> 6); w < 94; ++w) {
            int q = (w << 6) + lane;  // < 6144; pad rows give garbage bits (ignored)
            float4 Q = sbox[q];
            float qa = (Q.z - Q.x + 1.0f) * (Q.w - Q.y + 1.0f);
            float xx1 = fmaxf(B.x, Q.x);
            float yy1 = fmaxf(B.y, Q.y);
            float xx2 = fminf(B.z, Q.z);
            float yy2 = fminf(B.w, Q.w);
            float inter = fmaxf(xx2 - xx1 + 1.0f, 0.0f) * fmaxf(yy2 - yy1 + 1.0f, 0.0f);
            float iou = inter / (war + qa - inter);
            u64 bal = __ballot(iou > NMS_THRESH);
            if (lane == 0) row[w] = bal;
        }
    }
}

// ---------------------------------------------------------------------------
// Kernel 5: serial scan, single wave. Suppressed mask in registers (lane owns
// words 2*lane, 2*lane+1; bits >= 6000 pre-set). Two 8-row register banks
// slide forward: entering block k+1 refills the retiring bank with block k+2,
// issued ~8 keep-steps before first use (hides the L2/L3 miss latency).
// Uniform branch on bank parity keeps in-flight registers untouched.
// ---------------------------------------------------------------------------
#define LOADBANK(X, Y, BIDX)                                              \
    do {                                                                  \
        const u64* _rp = mask + (size_t)(BIDX) * 8 * MASK_W + w0;         \
        _Pragma("unroll") for (int _k = 0; _k < 8; ++_k) {                \
            X[_k] = _rp[0];                                               \
            Y[_k] = _rp[1];                                               \
            _rp += MASK_W;                                                \
        }                                                                 \
    } while (0)

__global__ void scan_kernel(const u64* __restrict__ mask,
                            const int* __restrict__ sidx,
                            int* __restrict__ out_idx,
                            float* __restrict__ out_valid) {
    int lane = threadIdx.x;
    int w0 = 2 * lane, w1 = w0 + 1;

    u64 m_lo = (w0 < 93) ? 0ULL : (w0 == 93 ? 0xFFFF000000000000ULL : ~0ULL);
    u64 m_hi = (w1 < 93) ? 0ULL : (w1 == 93 ? 0xFFFF000000000000ULL : ~0ULL);

    u64 ax[8], ay[8], bx[8], by[8];
#pragma unroll
    for (int k = 0; k < 8; ++k) { ax[k] = 0; ay[k] = 0; bx[k] = 0; by[k] = 0; }

    int curBlk = 0;
    if (lane < 48) {
        LOADBANK(ax, ay, 0);  // bank parity 0 <- block 0
        LOADBANK(bx, by, 1);  // bank parity 1 <- block 1
    }

    int r = 0;
    while (r < PADDING) {
        u64 z0 = ~m_lo, z1 = ~m_hi;
        u64 bal = __ballot((z0 | z1) != 0ULL);
        if (bal == 0ULL) break;
        int lsrc = (int)__ffsll(bal) - 1;
        int local = (z0 != 0ULL) ? ((int)__ffsll(z0) - 1) : (64 + (int)__ffsll(z1) - 1);
        int p = __shfl(lane * 128 + local, lsrc);  // wave-uniform

        int blk = p >> 3;
        if (blk >= curBlk + 2) {
            // long jump: synchronous reload of both banks (rare)
            if (lane < 48) {
                if ((blk & 1) == 0) {
                    LOADBANK(ax, ay, blk);
                    LOADBANK(bx, by, blk + 1);
                } else {
                    LOADBANK(bx, by, blk);
                    LOADBANK(ax, ay, blk + 1);
                }
            }
            curBlk = blk;
        } else if (blk == curBlk + 1) {
            // advance: refill retiring bank with block curBlk+2 (used >=8 steps later)
            if (lane < 48) {
                if ((curBlk & 1) == 0) LOADBANK(ax, ay, curBlk + 2);
                else                   LOADBANK(bx, by, curBlk + 2);
            }
            curBlk = blk;
        }

        int sel = p & 7;
        u64 vx, vy;
        if ((blk & 1) == 0) {  // uniform branch: touch only the live bank
            vx = ax[0]; vy = ay[0];
#pragma unroll
            for (int k = 1; k < 8; ++k)
                if (sel == k) { vx = ax[k]; vy = ay[k]; }
        } else {
            vx = bx[0]; vy = by[0];
#pragma unroll
            for (int k = 1; k < 8; ++k)
                if (sel == k) { vx = bx[k]; vy = by[k]; }
        }
        if (lane < 48) { m_lo |= vx; m_hi |= vy; }
        if (lane == 0) { out_idx[r] = sidx[p]; out_valid[r] = 1.0f; }
        ++r;
    }
    for (; r < PADDING; ++r) {
        if (lane == 0) { out_idx[r] = 0; out_valid[r] = 0.0f; }
    }
}

// ---------------------------------------------------------------------------
// Kernel 6: gather outputs. Grid (300, 4): y-dim splits the mask row copy.
// out layout: boxes [300*4] | scores [300*81] | masks [300*15876]
// ---------------------------------------------------------------------------
__global__ void gather_kernel(const float* __restrict__ pbox,
                              const float* __restrict__ scores,
                              const float* __restrict__ masks,
                              const int* __restrict__ idx,
                              const float* __restrict__ valid,
                              float* __restrict__ out) {
    int b = blockIdx.x;
    int part = blockIdx.y;
    int tid = threadIdx.x;
    int i = idx[b];
    float vf = valid[b];

    if (part == 0) {
        if (tid < 4) out[b * 4 + tid] = pbox[i * 4 + tid] * vf;
        if (tid < C) out[PADDING * 4 + b * C + tid] = scores[i * C + tid] * vf;
    }

    const float4* src = (const float4*)(masks + (size_t)i * MASK_ELEMS);
    float4* dst = (float4*)(out + PADDING * 4 + PADDING * C + (size_t)b * MASK_ELEMS);
    int end = min((part + 1) * 993, MASK_ELEMS / 4);
    for (int m = part * 993 + tid; m < end; m += 256) {
        float4 v = src[m];
        dst[m] = make_float4(v.x * vf, v.y * vf, v.z * vf, v.w * vf);
    }
}

extern "C" void kernel_launch(void* const* d_in, const int* in_sizes, int n_in,
                              void* d_out, int out_size, void* d_ws, size_t ws_size,
                              hipStream_t stream) {
    const float* meta      = (const float*)d_in[0];
    const float* deltas    = (const float*)d_in[1];
    const float* proposals = (const float*)d_in[2];
    const float* scores    = (const float*)d_in[3];
    const float* masks     = (const float*)d_in[4];
    float* out = (float*)d_out;

    // Workspace layout (bytes). mask MUST be first: the scan's lookahead may
    // prefetch (never use) up to row 6015, spilling into the arrays after it.
    char* ws = (char*)d_ws;
    u64*    mask      = (u64*)(ws);                 // 6000*96*8 = 4,608,000
    u64*    skey      = (u64*)(ws + 4608000);       // 6144*8    =    49,152
    float*  pbox      = (float*)(ws + 4657152);     // 6000*4*4  =    96,000
    int*    rank_part = (int*)(ws + 4753152);       // 8*6144*4  =   196,608
    int*    sidx      = (int*)(ws + 4949760);       // 6144*4    =    24,576
    float4* sbox      = (float4*)(ws + 4974336);    // 6144*16   =    98,304
    int*    out_idx   = (int*)(ws + 5072640);       // 300*4
    float*  out_valid = (float*)(ws + 5073840);     // 300*4

    decode_kernel<<<1500, 256, 0, stream>>>(meta, deltas, proposals, scores, pbox, skey);
    rank_kernel<<<dim3(24, NCHUNK), 256, 0, stream>>>(skey, rank_part);
    scatter_kernel<<<24, 256, 0, stream>>>(rank_part, pbox, sidx, sbox);
    iou_kernel<<<752, 256, 0, stream>>>(sbox, mask);
    scan_kernel<<<1, 64, 0, stream>>>(mask, sidx, out_idx, out_valid);
    gather_kernel<<<dim3(PADDING, 4), 256, 0, stream>>>(pbox, scores, masks, out_idx, out_valid, out);
}